// Round 17
// baseline (349.920 us; speedup 1.0000x reference)
//
#include <hip/hip_runtime.h>

// MoE: T=8192, D=1024, E=8, top-2, H=2730 (pad 2752), capacity=1024.
// R17: DAG-reordered pipeline, GEMMs reverted to R15-exact (R16's convert-in-
// gemm1 stole CU slots from GEMM TLP: 110->130, MfmaUtil 36->30).
//   K1 router (512 blk) -> K2 rank (64 blk, wave-coop)
//   -> K3 fused_bw: gather || wg/wu convert || wd convert || out-zero
//   -> K4 gemm1 (BM=256, 8 waves) -> K5 gemm2 (BM=256, 8 waves).
// Lessons: R5 dbuf -20%; R6 VGPR cliff -30%; R10 coarse vmcnt -8%;
// R16 BW-blocks+GEMM same launch -15%. BW blocks only mix with BW blocks.

typedef float  f4  __attribute__((ext_vector_type(4)));
typedef float  f2  __attribute__((ext_vector_type(2)));
typedef __bf16 bf8v __attribute__((ext_vector_type(8)));
typedef __bf16 bf4v __attribute__((ext_vector_type(4)));
typedef unsigned int u32;
typedef unsigned long long u64;
typedef u32 u4v __attribute__((ext_vector_type(4)));

#define NTOK 8192
#define DM   1024
#define NE   8
#define HD   2730
#define HP   2752
#define CAP  1024
#define RCH  8

__device__ __forceinline__ f4 mfma_bf16(bf8v a, bf8v b, f4 c) {
  return __builtin_amdgcn_mfma_f32_16x16x32_bf16(a, b, c, 0, 0, 0);
}

__device__ __forceinline__ void gl_lds16(const void* g, void* l) {
  __builtin_amdgcn_global_load_lds(
      (const __attribute__((address_space(1))) unsigned int*)g,
      (__attribute__((address_space(3))) unsigned int*)l, 16, 0, 0);
}

// ================= K1: router only (512 blocks, 16 tok/block) =================
__global__ __launch_bounds__(256) void router_kernel(
    const float* __restrict__ x, const float* __restrict__ gw, u64* __restrict__ recs) {
  __shared__ float gws[NE][DM];
  int bid = blockIdx.x;
  int tid = threadIdx.x;
  for (int i = tid * 4; i < NE * DM; i += 1024)
    *reinterpret_cast<f4*>(&gws[0][i]) = *reinterpret_cast<const f4*>(gw + i);
  __syncthreads();
  int lane = tid & 63, wave = tid >> 6;
  int tbase = bid * 16 + wave * 4;
#pragma unroll
  for (int tt = 0; tt < 4; ++tt) {
    int t = tbase + tt;
    const f4* xr = reinterpret_cast<const f4*>(x + (size_t)t * DM);
    float acc[NE];
#pragma unroll
    for (int e = 0; e < NE; ++e) acc[e] = 0.f;
#pragma unroll
    for (int i = 0; i < 4; ++i) {
      f4 xv = xr[i * 64 + lane];
#pragma unroll
      for (int e = 0; e < NE; ++e) {
        f4 gv = *reinterpret_cast<const f4*>(&gws[e][i * 256 + lane * 4]);
        acc[e] += xv[0] * gv[0] + xv[1] * gv[1] + xv[2] * gv[2] + xv[3] * gv[3];
      }
    }
#pragma unroll
    for (int e = 0; e < NE; ++e) {
      float v = acc[e];
#pragma unroll
      for (int off = 32; off > 0; off >>= 1) v += __shfl_xor(v, off);
      acc[e] = v;
    }
    if (lane == 0) {
      float l0 = -1e30f, l1 = -1e30f; int i0 = 0, i1 = 0;
#pragma unroll
      for (int e = 0; e < NE; ++e) {
        float v = acc[e];
        if (v > l0)      { l1 = l0; i1 = i0; l0 = v; i0 = e; }
        else if (v > l1) { l1 = v; i1 = e; }
      }
      float e1 = expf(l1 - l0);     // libm expf: p feeds rank ordering
      float s  = 1.f + e1;
      float p0 = 1.f / s, p1 = e1 / s;
      float s2 = p0 + p1;
      p0 /= s2; p1 /= s2;
      u32 pf0 = 0xFFFFFFFFu - (((u32)(2 * t)     << 3) | (u32)i0);
      u32 pf1 = 0xFFFFFFFFu - (((u32)(2 * t + 1) << 3) | (u32)i1);
      recs[2 * t]     = ((u64)__float_as_uint(p0) << 32) | pf0;
      recs[2 * t + 1] = ((u64)__float_as_uint(p1) << 32) | pf1;
    }
  }
}

// ================= K2: rank (64 blocks, wave-coop; R15-verified) =================
__global__ __launch_bounds__(1024) void rank_kernel(
    const u64* __restrict__ recs, int* __restrict__ etok, float* __restrict__ ep,
    int* __restrict__ ecnt) {
  __shared__ u64 keys[8192];
  __shared__ int lcnt;
  int bid = blockIdx.x;
  int tid = threadIdx.x;
  int e = bid / RCH;
  int c = bid % RCH;
  int lane = tid & 63;
  int wv = tid >> 6;
  if (tid == 0) lcnt = 0;
  __syncthreads();
  for (int s = tid; s < 2 * NTOK; s += 1024) {
    u64 r = recs[s];
    bool m = ((0xFFFFFFFFu - (u32)r) & 7u) == (u32)e;
    u64 mask = __ballot(m);
    int base = 0;
    if (lane == 0 && mask) base = atomicAdd(&lcnt, __popcll(mask));
    base = __shfl(base, 0);
    if (m) {
      int off = __popcll(mask & ((1ull << lane) - 1ull));
      keys[base + off] = r;
    }
  }
  __syncthreads();
  int n = lcnt;
  int sbase = c * (2 * NTOK / RCH) + wv * (2 * NTOK / RCH / 16);
#pragma unroll 4
  for (int i = 0; i < (2 * NTOK / RCH / 16); ++i) {
    u64 ki = recs[sbase + i];
    if (((0xFFFFFFFFu - (u32)ki) & 7u) != (u32)e) continue;
    int r = 0;
    for (int j = lane; j < n; j += 64) r += (keys[j] > ki);
#pragma unroll
    for (int off = 32; off > 0; off >>= 1) r += __shfl_xor(r, off);
    if (lane == 0 && r < CAP) {
      u32 v = 0xFFFFFFFFu - (u32)ki;
      etok[e * CAP + r] = (int)(v >> 3);
      ep[e * CAP + r]   = __uint_as_float((u32)(ki >> 32));
    }
  }
  if (c == 0 && tid == 0) ecnt[e] = n < CAP ? n : CAP;
}

// ================= K3: fused BW — gather || wg/wu convert || wd convert || zero =================
// [0,1024): gather 8 rows/blk; [1024,23040): wg/wu; [23040,34048): wd; [34048,35072): zero.
#define K3_GA0 0
#define K3_GU0 1024
#define K3_GU1 (1024 + 11008)
#define K3_WD0 (1024 + 22016)
#define K3_ZR0 (K3_WD0 + 11008)
#define K3_N   (K3_ZR0 + 1024)
__global__ __launch_bounds__(256) void fused_bw(
    const float* __restrict__ x, const int* __restrict__ etok, const int* __restrict__ ecnt,
    const float* __restrict__ wg, const float* __restrict__ wu, const float* __restrict__ wd,
    __bf16* __restrict__ Xe, __bf16* __restrict__ wgb, __bf16* __restrict__ wub,
    __bf16* __restrict__ wdb, float* __restrict__ out) {
  int bid = blockIdx.x;
  int tid = threadIdx.x;

  if (bid < K3_GU0) {
    // ---- gather kept tokens -> bf16, 8 rows/block (R15-verified) ----
    int base = bid * 8;
    int e = base >> 10;
    int ne = ecnt[e];
#pragma unroll
    for (int i = 0; i < 8; ++i) {
      int gr = base + i;
      int r = gr & 1023;
      __bf16* dst = Xe + (size_t)gr * DM;
      bf4v o;
      if (r < ne) {
        int tok = etok[e * CAP + r] >> 1;
        f4 v = reinterpret_cast<const f4*>(x + (size_t)tok * DM)[tid];
        o[0] = (__bf16)v[0]; o[1] = (__bf16)v[1]; o[2] = (__bf16)v[2]; o[3] = (__bf16)v[3];
      } else {
        o[0] = (__bf16)0.f; o[1] = (__bf16)0.f; o[2] = (__bf16)0.f; o[3] = (__bf16)0.f;
      }
      reinterpret_cast<bf4v*>(dst)[tid] = o;
    }
  } else if (bid < K3_WD0) {
    // ---- wg/wu: [NE][HD][DM] f32 -> [NE][HP][DM] bf16 (R15-verified) ----
    int u = (bid < K3_GU1) ? (bid - K3_GU0) : (bid - K3_GU1);
    const float* src = (bid < K3_GU1) ? wg : wu;
    __bf16* dst = (bid < K3_GU1) ? wgb : wub;
    int e = u / 1376;
    int idx = (u % 1376) * 256 + tid;
    int row = idx >> 7;
    int c = (idx & 127) << 3;
    bf8v o;
    if (row < HD) {
      const float* s = src + ((size_t)e * HD + row) * DM + c;
      f4 a = *reinterpret_cast<const f4*>(s);
      f4 b = *reinterpret_cast<const f4*>(s + 4);
#pragma unroll
      for (int q = 0; q < 4; ++q) { o[q] = (__bf16)a[q]; o[q + 4] = (__bf16)b[q]; }
    } else {
#pragma unroll
      for (int q = 0; q < 8; ++q) o[q] = (__bf16)0.f;
    }
    *reinterpret_cast<bf8v*>(dst + ((size_t)e * HP + row) * DM + c) = o;
  } else if (bid < K3_ZR0) {
    // ---- wd: [NE][DM][HD] f32 -> [NE][DM][HP] bf16 (R8-verified decode) ----
    int u = bid - K3_WD0;
    int e = u / 1376;
    int idx = (u % 1376) * 256 + tid;
    int row = idx / 344;
    int c = (idx % 344) << 3;
    const float* s = wd + ((size_t)e * DM + row) * HD + c;
    bf8v o;
    if (c + 8 <= HD) {
      f2 q0 = *reinterpret_cast<const f2*>(s);
      f2 q1 = *reinterpret_cast<const f2*>(s + 2);
      f2 q2 = *reinterpret_cast<const f2*>(s + 4);
      f2 q3 = *reinterpret_cast<const f2*>(s + 6);
      o[0] = (__bf16)q0[0]; o[1] = (__bf16)q0[1]; o[2] = (__bf16)q1[0]; o[3] = (__bf16)q1[1];
      o[4] = (__bf16)q2[0]; o[5] = (__bf16)q2[1]; o[6] = (__bf16)q3[0]; o[7] = (__bf16)q3[1];
    } else {
#pragma unroll
      for (int q = 0; q < 8; ++q) o[q] = (c + q < HD) ? (__bf16)s[q] : (__bf16)0.f;
    }
    *reinterpret_cast<bf8v*>(wdb + ((size_t)e * DM + row) * HP + c) = o;
  } else {
    // ---- zero out[]: 1024 blocks x 256 thr x 8 f4 (R16-verified) ----
    int z = bid - K3_ZR0;
    f4* o4 = reinterpret_cast<f4*>(out);
    f4 zv = (f4){0.f, 0.f, 0.f, 0.f};
#pragma unroll
    for (int i = 0; i < 8; ++i) o4[(size_t)z * 2048 + i * 256 + tid] = zv;
  }
}

// ============ GEMM1 (R15-exact): BM=256, 8 waves, wave 64x32 dual (G+U), 48KB LDS ============
__global__ __launch_bounds__(512) void gemm1_swiglu_bf(
    const __bf16* __restrict__ Xe, const __bf16* __restrict__ wgb, const __bf16* __restrict__ wub,
    const int* __restrict__ ecnt, __bf16* __restrict__ Hbuf) {
  int bid = blockIdx.x;                  // 1376 = 8 XCD * 172
  int e   = bid & 7;
  int rem = bid >> 3;
  int pm  = rem & 3;
  int pn  = rem >> 2;
  int ne = ecnt[e];
  int m0 = pm * 256, n0 = pn * 64;
  if (m0 >= ne) return;

  __shared__ __align__(16) __bf16 As[256 * 64];
  __shared__ __align__(16) __bf16 Bgs[64 * 64];
  __shared__ __align__(16) __bf16 Bus[64 * 64];

  int tid = threadIdx.x;
  int lane = tid & 63, wave = tid >> 6;
  int wm = wave >> 1, wn = wave & 1;
  int lr = lane >> 3;
  int scol = (((lane & 7) << 4) ^ (lr << 4)) >> 1;

  f4 accG[4][2], accU[4][2];
#pragma unroll
  for (int m = 0; m < 4; ++m)
#pragma unroll
    for (int n = 0; n < 2; ++n) { accG[m][n] = (f4){0,0,0,0}; accU[m][n] = (f4){0,0,0,0}; }

  const __bf16* Ab = Xe + ((size_t)(e * CAP + m0)) * DM;
  const __bf16* Gb = wgb + (size_t)e * HP * DM + (size_t)n0 * DM;
  const __bf16* Ub = wub + (size_t)e * HP * DM + (size_t)n0 * DM;

  for (int kt = 0; kt < 16; ++kt) {
    int k0 = kt * 64;
#pragma unroll
    for (int i = 0; i < 4; ++i) {
      int rb = i * 64 + wave * 8 + lr;
      gl_lds16(Ab + (size_t)rb * DM + k0 + scol, (char*)As + i * 8192 + wave * 1024);
    }
    {
      int rb = wave * 8 + lr;
      gl_lds16(Gb + (size_t)rb * DM + k0 + scol, (char*)Bgs + wave * 1024);
      gl_lds16(Ub + (size_t)rb * DM + k0 + scol, (char*)Bus + wave * 1024);
    }
    __syncthreads();
#pragma unroll
    for (int kk = 0; kk < 2; ++kk) {
      int kb = kk * 64 + ((lane >> 4) << 4);
      bf8v af[4];
#pragma unroll
      for (int m = 0; m < 4; ++m) {
        int row = wm * 64 + m * 16 + (lane & 15);
        af[m] = *reinterpret_cast<const bf8v*>(
            reinterpret_cast<const char*>(As) + ((row * 128 + kb) ^ ((row & 7) << 4)));
      }
      bf8v bg[2], bu[2];
#pragma unroll
      for (int n = 0; n < 2; ++n) {
        int row = wn * 32 + n * 16 + (lane & 15);
        int off = (row * 128 + kb) ^ ((row & 7) << 4);
        bg[n] = *reinterpret_cast<const bf8v*>(reinterpret_cast<const char*>(Bgs) + off);
        bu[n] = *reinterpret_cast<const bf8v*>(reinterpret_cast<const char*>(Bus) + off);
      }
#pragma unroll
      for (int m = 0; m < 4; ++m)
#pragma unroll
        for (int n = 0; n < 2; ++n) {
          accG[m][n] = mfma_bf16(af[m], bg[n], accG[m][n]);
          accU[m][n] = mfma_bf16(af[m], bu[n], accU[m][n]);
        }
    }
    __syncthreads();
  }

  __bf16* hb = Hbuf + (size_t)e * CAP * HP;
#pragma unroll
  for (int m = 0; m < 4; ++m)
#pragma unroll
    for (int n = 0; n < 2; ++n)
#pragma unroll
      for (int j = 0; j < 4; ++j) {
        int row = m0 + wm * 64 + m * 16 + ((lane >> 4) << 2) + j;
        int col = n0 + wn * 32 + n * 16 + (lane & 15);
        float g = accG[m][n][j];
        float u = accU[m][n][j];
        float h = g / (1.f + __expf(-g)) * u;
        hb[(size_t)row * HP + col] = (__bf16)h;
      }
}

// ============ GEMM2 (R15-exact): BM=256, 8 waves, wave 64x32, 40KB LDS, K=2752 ============
__global__ __launch_bounds__(512) void gemm2_down_bf(
    const __bf16* __restrict__ Hbuf, const __bf16* __restrict__ wdb,
    const int* __restrict__ ecnt, const int* __restrict__ etok, const float* __restrict__ ep,
    float* __restrict__ out) {
  int bid = blockIdx.x;                  // 512 = 8 XCD * 64
  int e   = bid & 7;
  int rem = bid >> 3;
  int pm  = rem & 3;
  int pn  = rem >> 2;
  int ne = ecnt[e];
  int m0 = pm * 256, n0 = pn * 64;
  if (m0 >= ne) return;

  __shared__ __align__(16) __bf16 As[256 * 64];
  __shared__ __align__(16) __bf16 Bs[64 * 64];

  int tid = threadIdx.x;
  int lane = tid & 63, wave = tid >> 6;
  int wm = wave >> 1, wn = wave & 1;
  int lr = lane >> 3;
  int scol = (((lane & 7) << 4) ^ (lr << 4)) >> 1;

  f4 acc[4][2];
#pragma unroll
  for (int m = 0; m < 4; ++m)
#pragma unroll
    for (int n = 0; n < 2; ++n) acc[m][n] = (f4){0,0,0,0};

  const __bf16* Ab = Hbuf + (size_t)(e * CAP + m0) * HP;
  const __bf16* Bb = wdb + (size_t)e * DM * HP + (size_t)n0 * HP;

  for (int kt = 0; kt < HP / 64; ++kt) {
    int k0 = kt * 64;
#pragma unroll
    for (int i = 0; i < 4; ++i) {
      int rb = i * 64 + wave * 8 + lr;
      gl_lds16(Ab + (size_t)rb * HP + k0 + scol, (char*)As + i * 8192 + wave * 1024);
    }
    {
      int rb = wave * 8 + lr;
      gl_lds16(Bb + (size_t)rb * HP + k0 + scol, (char*)Bs + wave * 1024);
    }
    __syncthreads();
#pragma unroll
    for (int kk = 0; kk < 2; ++kk) {
      int kb = kk * 64 + ((lane >> 4) << 4);
      bf8v af[4];
#pragma unroll
      for (int m = 0; m < 4; ++m) {
        int row = wm * 64 + m * 16 + (lane & 15);
        af[m] = *reinterpret_cast<const bf8v*>(
            reinterpret_cast<const char*>(As) + ((row * 128 + kb) ^ ((row & 7) << 4)));
      }
      bf8v bfr[2];
#pragma unroll
      for (int n = 0; n < 2; ++n) {
        int row = wn * 32 + n * 16 + (lane & 15);
        bfr[n] = *reinterpret_cast<const bf8v*>(
            reinterpret_cast<const char*>(Bs) + ((row * 128 + kb) ^ ((row & 7) << 4)));
      }
#pragma unroll
      for (int m = 0; m < 4; ++m)
#pragma unroll
        for (int n = 0; n < 2; ++n)
          acc[m][n] = mfma_bf16(af[m], bfr[n], acc[m][n]);
    }
    __syncthreads();
  }

#pragma unroll
  for (int m = 0; m < 4; ++m)
#pragma unroll
    for (int j = 0; j < 4; ++j) {
      int row = m0 + wm * 64 + m * 16 + ((lane >> 4) << 2) + j;
      if (row < ne) {
        float p  = ep[e * CAP + row];
        int tok  = etok[e * CAP + row] >> 1;
        float* orow = out + (size_t)tok * DM;
#pragma unroll
        for (int n = 0; n < 2; ++n) {
          int col = n0 + wn * 32 + n * 16 + (lane & 15);
          atomicAdd(orow + col, acc[m][n][j] * p);   // <=2 adds/elem, deterministic
        }
      }
    }
}

// ---------------- launch ----------------
extern "C" void kernel_launch(void* const* d_in, const int* in_sizes, int n_in,
                              void* d_out, int out_size, void* d_ws, size_t ws_size,
                              hipStream_t stream) {
  const float* x     = (const float*)d_in[0];
  const float* gw    = (const float*)d_in[1];
  const float* wgate = (const float*)d_in[2];
  const float* wup   = (const float*)d_in[3];
  const float* wdown = (const float*)d_in[4];
  float* out = (float*)d_out;
  char* ws = (char*)d_ws;

  u64*   recs = (u64*)  (ws + 0);
  int*   etok = (int*)  (ws + 131072);
  float* ep   = (float*)(ws + 163840);
  int*   ecnt = (int*)  (ws + 196608);
  __bf16* Xe  = (__bf16*)(ws + 196864);
  __bf16* Hbuf= (__bf16*)(ws + 16974080);
  __bf16* wgb = (__bf16*)(ws + 62062848);
  __bf16* wub = (__bf16*)(ws + 107151616);
  __bf16* wdb = (__bf16*)(ws + 152240384);

  router_kernel<<<512, 256, 0, stream>>>(x, gw, recs);
  rank_kernel<<<NE * RCH, 1024, 0, stream>>>(recs, etok, ep, ecnt);
  fused_bw<<<K3_N, 256, 0, stream>>>(x, etok, ecnt, wgate, wup, wdown,
                                     Xe, wgb, wub, wdb, out);
  gemm1_swiglu_bf<<<8 * 172, 512, 0, stream>>>(Xe, wgb, wub, ecnt, Hbuf);
  gemm2_down_bf<<<8 * 64, 512, 0, stream>>>(Hbuf, wdb, ecnt, etok, ep, out);
}

// Round 18
// 324.105 us; speedup vs baseline: 1.0796x; 1.0796x over previous
//
#include <hip/hip_runtime.h>

// MoE: T=8192, D=1024, E=8, top-2, H=2730 (pad 2752), capacity=1024.
// R18 = R15 verbatim (best, 327us) + gemm2 retiled 128x128 (65 vs 52 FLOP/B).
// Pipeline: prep1(router || wg/wu cvt) -> prep2(rank || wd cvt || zero)
//   -> gather -> gemm1(BM=256, 8w) -> gemm2(128x128, 8w).
// Lessons: R5 dbuf -20%; R6 VGPR cliff -30%; R10 coarse vmcnt -8%;
// R16 BW+GEMM same launch -15%; R17 un-hidden serial prefix -7%.

typedef float  f4  __attribute__((ext_vector_type(4)));
typedef float  f2  __attribute__((ext_vector_type(2)));
typedef __bf16 bf8v __attribute__((ext_vector_type(8)));
typedef __bf16 bf4v __attribute__((ext_vector_type(4)));
typedef unsigned int u32;
typedef unsigned long long u64;
typedef u32 u4v __attribute__((ext_vector_type(4)));

#define NTOK 8192
#define DM   1024
#define NE   8
#define HD   2730
#define HP   2752
#define CAP  1024
#define RCH  8

__device__ __forceinline__ f4 mfma_bf16(bf8v a, bf8v b, f4 c) {
  return __builtin_amdgcn_mfma_f32_16x16x32_bf16(a, b, c, 0, 0, 0);
}

__device__ __forceinline__ void gl_lds16(const void* g, void* l) {
  __builtin_amdgcn_global_load_lds(
      (const __attribute__((address_space(1))) unsigned int*)g,
      (__attribute__((address_space(3))) unsigned int*)l, 16, 0, 0);
}

// ================= K1: router + wg/wu convert =================
#define K1_GU0 512
#define K1_GU1 (512 + 11008)
#define K1_N   (512 + 22016)
__global__ __launch_bounds__(256) void fused_prep1(
    const float* __restrict__ x, const float* __restrict__ gw,
    const float* __restrict__ wg, const float* __restrict__ wu,
    u64* __restrict__ recs, __bf16* __restrict__ wgb, __bf16* __restrict__ wub) {
  __shared__ float gws[NE][DM];
  int bid = blockIdx.x;
  int tid = threadIdx.x;

  if (bid < K1_GU0) {
    for (int i = tid * 4; i < NE * DM; i += 1024)
      *reinterpret_cast<f4*>(&gws[0][i]) = *reinterpret_cast<const f4*>(gw + i);
    __syncthreads();
    int lane = tid & 63, wave = tid >> 6;
    int tbase = bid * 16 + wave * 4;
#pragma unroll
    for (int tt = 0; tt < 4; ++tt) {
      int t = tbase + tt;
      const f4* xr = reinterpret_cast<const f4*>(x + (size_t)t * DM);
      float acc[NE];
#pragma unroll
      for (int e = 0; e < NE; ++e) acc[e] = 0.f;
#pragma unroll
      for (int i = 0; i < 4; ++i) {
        f4 xv = xr[i * 64 + lane];
#pragma unroll
        for (int e = 0; e < NE; ++e) {
          f4 gv = *reinterpret_cast<const f4*>(&gws[e][i * 256 + lane * 4]);
          acc[e] += xv[0] * gv[0] + xv[1] * gv[1] + xv[2] * gv[2] + xv[3] * gv[3];
        }
      }
#pragma unroll
      for (int e = 0; e < NE; ++e) {
        float v = acc[e];
#pragma unroll
        for (int off = 32; off > 0; off >>= 1) v += __shfl_xor(v, off);
        acc[e] = v;
      }
      if (lane == 0) {
        float l0 = -1e30f, l1 = -1e30f; int i0 = 0, i1 = 0;
#pragma unroll
        for (int e = 0; e < NE; ++e) {
          float v = acc[e];
          if (v > l0)      { l1 = l0; i1 = i0; l0 = v; i0 = e; }
          else if (v > l1) { l1 = v; i1 = e; }
        }
        float e1 = expf(l1 - l0);     // libm expf: p feeds rank ordering
        float s  = 1.f + e1;
        float p0 = 1.f / s, p1 = e1 / s;
        float s2 = p0 + p1;
        p0 /= s2; p1 /= s2;
        u32 pf0 = 0xFFFFFFFFu - (((u32)(2 * t)     << 3) | (u32)i0);
        u32 pf1 = 0xFFFFFFFFu - (((u32)(2 * t + 1) << 3) | (u32)i1);
        recs[2 * t]     = ((u64)__float_as_uint(p0) << 32) | pf0;
        recs[2 * t + 1] = ((u64)__float_as_uint(p1) << 32) | pf1;
      }
    }
  } else {
    int u = (bid < K1_GU1) ? (bid - K1_GU0) : (bid - K1_GU1);
    const float* src = (bid < K1_GU1) ? wg : wu;
    __bf16* dst = (bid < K1_GU1) ? wgb : wub;
    int e = u / 1376;
    int idx = (u % 1376) * 256 + tid;
    int row = idx >> 7;
    int c = (idx & 127) << 3;
    bf8v o;
    if (row < HD) {
      const float* s = src + ((size_t)e * HD + row) * DM + c;
      f4 a = *reinterpret_cast<const f4*>(s);
      f4 b = *reinterpret_cast<const f4*>(s + 4);
#pragma unroll
      for (int q = 0; q < 4; ++q) { o[q] = (__bf16)a[q]; o[q + 4] = (__bf16)b[q]; }
    } else {
#pragma unroll
      for (int q = 0; q < 8; ++q) o[q] = (__bf16)0.f;
    }
    *reinterpret_cast<bf8v*>(dst + ((size_t)e * HP + row) * DM + c) = o;
  }
}

// ================= K2: rank (wave-coop) + wdown convert + out-zero (1024 thr) =================
#define K2_WD0 (NE * RCH)
#define K2_ZR0 (K2_WD0 + 2752)
#define K2_N   (K2_ZR0 + 256)
__global__ __launch_bounds__(1024) void fused_prep2(
    const u64* __restrict__ recs, const float* __restrict__ wd,
    int* __restrict__ etok, float* __restrict__ ep, int* __restrict__ ecnt,
    __bf16* __restrict__ wdb, float* __restrict__ out) {
  __shared__ u64 keys[8192];
  __shared__ int lcnt;
  int bid = blockIdx.x;
  int tid = threadIdx.x;

  if (bid < K2_WD0) {
    int e = bid / RCH;
    int c = bid % RCH;
    int lane = tid & 63;
    int wv = tid >> 6;
    if (tid == 0) lcnt = 0;
    __syncthreads();
    for (int s = tid; s < 2 * NTOK; s += 1024) {
      u64 r = recs[s];
      bool m = ((0xFFFFFFFFu - (u32)r) & 7u) == (u32)e;
      u64 mask = __ballot(m);
      int base = 0;
      if (lane == 0 && mask) base = atomicAdd(&lcnt, __popcll(mask));
      base = __shfl(base, 0);
      if (m) {
        int off = __popcll(mask & ((1ull << lane) - 1ull));
        keys[base + off] = r;
      }
    }
    __syncthreads();
    int n = lcnt;
    int sbase = c * (2 * NTOK / RCH) + wv * (2 * NTOK / RCH / 16);
#pragma unroll 4
    for (int i = 0; i < (2 * NTOK / RCH / 16); ++i) {
      u64 ki = recs[sbase + i];
      if (((0xFFFFFFFFu - (u32)ki) & 7u) != (u32)e) continue;
      int r = 0;
      for (int j = lane; j < n; j += 64) r += (keys[j] > ki);
#pragma unroll
      for (int off = 32; off > 0; off >>= 1) r += __shfl_xor(r, off);
      if (lane == 0 && r < CAP) {
        u32 v = 0xFFFFFFFFu - (u32)ki;
        etok[e * CAP + r] = (int)(v >> 3);
        ep[e * CAP + r]   = __uint_as_float((u32)(ki >> 32));
      }
    }
    if (c == 0 && tid == 0) ecnt[e] = n < CAP ? n : CAP;
  } else if (bid < K2_ZR0) {
    int u = bid - K2_WD0;
    int e = u / 344;
    int idx = (u % 344) * 1024 + tid;
    int row = idx / 344;
    int c = (idx % 344) << 3;
    const float* s = wd + ((size_t)e * DM + row) * HD + c;
    bf8v o;
    if (c + 8 <= HD) {
      f2 q0 = *reinterpret_cast<const f2*>(s);
      f2 q1 = *reinterpret_cast<const f2*>(s + 2);
      f2 q2 = *reinterpret_cast<const f2*>(s + 4);
      f2 q3 = *reinterpret_cast<const f2*>(s + 6);
      o[0] = (__bf16)q0[0]; o[1] = (__bf16)q0[1]; o[2] = (__bf16)q1[0]; o[3] = (__bf16)q1[1];
      o[4] = (__bf16)q2[0]; o[5] = (__bf16)q2[1]; o[6] = (__bf16)q3[0]; o[7] = (__bf16)q3[1];
    } else {
#pragma unroll
      for (int q = 0; q < 8; ++q) o[q] = (c + q < HD) ? (__bf16)s[q] : (__bf16)0.f;
    }
    *reinterpret_cast<bf8v*>(wdb + ((size_t)e * DM + row) * HP + c) = o;
  } else {
    int z = bid - K2_ZR0;
    f4* o4 = reinterpret_cast<f4*>(out);
    f4 zv = (f4){0.f, 0.f, 0.f, 0.f};
#pragma unroll
    for (int i = 0; i < 8; ++i) o4[(size_t)z * 8192 + i * 1024 + tid] = zv;
  }
}

// ---------------- gather kept tokens -> bf16, 8 rows per block ----------------
__global__ __launch_bounds__(256) void gather_kernel(
    const float* __restrict__ x, const int* __restrict__ etok, const int* __restrict__ ecnt,
    __bf16* __restrict__ Xe) {
  int base = blockIdx.x * 8;
  int e = base >> 10;
  int ne = ecnt[e];
  int tid = threadIdx.x;
#pragma unroll
  for (int i = 0; i < 8; ++i) {
    int gr = base + i;
    int r = gr & 1023;
    __bf16* dst = Xe + (size_t)gr * DM;
    bf4v o;
    if (r < ne) {
      int tok = etok[e * CAP + r] >> 1;
      f4 v = reinterpret_cast<const f4*>(x + (size_t)tok * DM)[tid];
      o[0] = (__bf16)v[0]; o[1] = (__bf16)v[1]; o[2] = (__bf16)v[2]; o[3] = (__bf16)v[3];
    } else {
      o[0] = (__bf16)0.f; o[1] = (__bf16)0.f; o[2] = (__bf16)0.f; o[3] = (__bf16)0.f;
    }
    reinterpret_cast<bf4v*>(dst)[tid] = o;
  }
}

// ============ GEMM1 (R15-exact): BM=256, 8 waves, wave 64x32 dual (G+U), 48KB LDS ============
__global__ __launch_bounds__(512) void gemm1_swiglu_bf(
    const __bf16* __restrict__ Xe, const __bf16* __restrict__ wgb, const __bf16* __restrict__ wub,
    const int* __restrict__ ecnt, __bf16* __restrict__ Hbuf) {
  int bid = blockIdx.x;                  // 1376 = 8 XCD * 172
  int e   = bid & 7;
  int rem = bid >> 3;
  int pm  = rem & 3;
  int pn  = rem >> 2;
  int ne = ecnt[e];
  int m0 = pm * 256, n0 = pn * 64;
  if (m0 >= ne) return;

  __shared__ __align__(16) __bf16 As[256 * 64];
  __shared__ __align__(16) __bf16 Bgs[64 * 64];
  __shared__ __align__(16) __bf16 Bus[64 * 64];

  int tid = threadIdx.x;
  int lane = tid & 63, wave = tid >> 6;
  int wm = wave >> 1, wn = wave & 1;
  int lr = lane >> 3;
  int scol = (((lane & 7) << 4) ^ (lr << 4)) >> 1;

  f4 accG[4][2], accU[4][2];
#pragma unroll
  for (int m = 0; m < 4; ++m)
#pragma unroll
    for (int n = 0; n < 2; ++n) { accG[m][n] = (f4){0,0,0,0}; accU[m][n] = (f4){0,0,0,0}; }

  const __bf16* Ab = Xe + ((size_t)(e * CAP + m0)) * DM;
  const __bf16* Gb = wgb + (size_t)e * HP * DM + (size_t)n0 * DM;
  const __bf16* Ub = wub + (size_t)e * HP * DM + (size_t)n0 * DM;

  for (int kt = 0; kt < 16; ++kt) {
    int k0 = kt * 64;
#pragma unroll
    for (int i = 0; i < 4; ++i) {
      int rb = i * 64 + wave * 8 + lr;
      gl_lds16(Ab + (size_t)rb * DM + k0 + scol, (char*)As + i * 8192 + wave * 1024);
    }
    {
      int rb = wave * 8 + lr;
      gl_lds16(Gb + (size_t)rb * DM + k0 + scol, (char*)Bgs + wave * 1024);
      gl_lds16(Ub + (size_t)rb * DM + k0 + scol, (char*)Bus + wave * 1024);
    }
    __syncthreads();
#pragma unroll
    for (int kk = 0; kk < 2; ++kk) {
      int kb = kk * 64 + ((lane >> 4) << 4);
      bf8v af[4];
#pragma unroll
      for (int m = 0; m < 4; ++m) {
        int row = wm * 64 + m * 16 + (lane & 15);
        af[m] = *reinterpret_cast<const bf8v*>(
            reinterpret_cast<const char*>(As) + ((row * 128 + kb) ^ ((row & 7) << 4)));
      }
      bf8v bg[2], bu[2];
#pragma unroll
      for (int n = 0; n < 2; ++n) {
        int row = wn * 32 + n * 16 + (lane & 15);
        int off = (row * 128 + kb) ^ ((row & 7) << 4);
        bg[n] = *reinterpret_cast<const bf8v*>(reinterpret_cast<const char*>(Bgs) + off);
        bu[n] = *reinterpret_cast<const bf8v*>(reinterpret_cast<const char*>(Bus) + off);
      }
#pragma unroll
      for (int m = 0; m < 4; ++m)
#pragma unroll
        for (int n = 0; n < 2; ++n) {
          accG[m][n] = mfma_bf16(af[m], bg[n], accG[m][n]);
          accU[m][n] = mfma_bf16(af[m], bu[n], accU[m][n]);
        }
    }
    __syncthreads();
  }

  __bf16* hb = Hbuf + (size_t)e * CAP * HP;
#pragma unroll
  for (int m = 0; m < 4; ++m)
#pragma unroll
    for (int n = 0; n < 2; ++n)
#pragma unroll
      for (int j = 0; j < 4; ++j) {
        int row = m0 + wm * 64 + m * 16 + ((lane >> 4) << 2) + j;
        int col = n0 + wn * 32 + n * 16 + (lane & 15);
        float g = accG[m][n][j];
        float u = accU[m][n][j];
        float h = g / (1.f + __expf(-g)) * u;
        hb[(size_t)row * HP + col] = (__bf16)h;
      }
}

// ============ GEMM2 retiled: 128x128 tile, 8 waves (2Mx4N of 64x32), 32KB LDS ============
__global__ __launch_bounds__(512) void gemm2_down_bf(
    const __bf16* __restrict__ Hbuf, const __bf16* __restrict__ wdb,
    const int* __restrict__ ecnt, const int* __restrict__ etok, const float* __restrict__ ep,
    float* __restrict__ out) {
  int bid = blockIdx.x;                  // 512 = 8 XCD * 64
  int e   = bid & 7;
  int rem = bid >> 3;                    // 0..63
  int pm  = rem & 7;                     // 8 m-tiles of 128
  int pn  = rem >> 3;                    // 8 n-tiles of 128
  int ne = ecnt[e];
  int m0 = pm * 128, n0 = pn * 128;
  if (m0 >= ne) return;

  __shared__ __align__(16) __bf16 As[128 * 64];    // 16 KB
  __shared__ __align__(16) __bf16 Bs[128 * 64];    // 16 KB

  int tid = threadIdx.x;
  int lane = tid & 63, wave = tid >> 6;   // 8 waves
  int wm = wave >> 2, wn = wave & 3;      // 2M x 4N, wave tile 64x32
  int lr = lane >> 3;
  int scol = (((lane & 7) << 4) ^ (lr << 4)) >> 1;

  f4 acc[4][2];
#pragma unroll
  for (int m = 0; m < 4; ++m)
#pragma unroll
    for (int n = 0; n < 2; ++n) acc[m][n] = (f4){0,0,0,0};

  const __bf16* Ab = Hbuf + (size_t)(e * CAP + m0) * HP;
  const __bf16* Bb = wdb + (size_t)e * DM * HP + (size_t)n0 * HP;

  for (int kt = 0; kt < HP / 64; ++kt) {       // 43 steps
    int k0 = kt * 64;
#pragma unroll
    for (int i = 0; i < 2; ++i) {              // A: 128 rows (2 x 8 waves x 8 rows)
      int rb = i * 64 + wave * 8 + lr;
      gl_lds16(Ab + (size_t)rb * HP + k0 + scol, (char*)As + i * 8192 + wave * 1024);
    }
#pragma unroll
    for (int i = 0; i < 2; ++i) {              // B: 128 rows
      int rb = i * 64 + wave * 8 + lr;
      gl_lds16(Bb + (size_t)rb * HP + k0 + scol, (char*)Bs + i * 8192 + wave * 1024);
    }
    __syncthreads();
#pragma unroll
    for (int kk = 0; kk < 2; ++kk) {
      int kb = kk * 64 + ((lane >> 4) << 4);
      bf8v af[4];
#pragma unroll
      for (int m = 0; m < 4; ++m) {
        int row = wm * 64 + m * 16 + (lane & 15);
        af[m] = *reinterpret_cast<const bf8v*>(
            reinterpret_cast<const char*>(As) + ((row * 128 + kb) ^ ((row & 7) << 4)));
      }
      bf8v bfr[2];
#pragma unroll
      for (int n = 0; n < 2; ++n) {
        int row = wn * 32 + n * 16 + (lane & 15);
        bfr[n] = *reinterpret_cast<const bf8v*>(
            reinterpret_cast<const char*>(Bs) + ((row * 128 + kb) ^ ((row & 7) << 4)));
      }
#pragma unroll
      for (int m = 0; m < 4; ++m)
#pragma unroll
        for (int n = 0; n < 2; ++n)
          acc[m][n] = mfma_bf16(af[m], bfr[n], acc[m][n]);
    }
    __syncthreads();
  }

#pragma unroll
  for (int m = 0; m < 4; ++m)
#pragma unroll
    for (int j = 0; j < 4; ++j) {
      int row = m0 + wm * 64 + m * 16 + ((lane >> 4) << 2) + j;
      if (row < ne) {
        float p  = ep[e * CAP + row];
        int tok  = etok[e * CAP + row] >> 1;
        float* orow = out + (size_t)tok * DM;
#pragma unroll
        for (int n = 0; n < 2; ++n) {
          int col = n0 + wn * 32 + n * 16 + (lane & 15);
          atomicAdd(orow + col, acc[m][n][j] * p);   // <=2 adds/elem, deterministic
        }
      }
    }
}

// ---------------- launch ----------------
extern "C" void kernel_launch(void* const* d_in, const int* in_sizes, int n_in,
                              void* d_out, int out_size, void* d_ws, size_t ws_size,
                              hipStream_t stream) {
  const float* x     = (const float*)d_in[0];
  const float* gw    = (const float*)d_in[1];
  const float* wgate = (const float*)d_in[2];
  const float* wup   = (const float*)d_in[3];
  const float* wdown = (const float*)d_in[4];
  float* out = (float*)d_out;
  char* ws = (char*)d_ws;

  u64*   recs = (u64*)  (ws + 0);
  int*   etok = (int*)  (ws + 131072);
  float* ep   = (float*)(ws + 163840);
  int*   ecnt = (int*)  (ws + 196608);
  __bf16* Xe  = (__bf16*)(ws + 196864);
  __bf16* Hbuf= (__bf16*)(ws + 16974080);
  __bf16* wgb = (__bf16*)(ws + 62062848);
  __bf16* wub = (__bf16*)(ws + 107151616);
  __bf16* wdb = (__bf16*)(ws + 152240384);

  fused_prep1<<<K1_N, 256, 0, stream>>>(x, gw, wgate, wup, recs, wgb, wub);
  fused_prep2<<<K2_N, 1024, 0, stream>>>(recs, wdown, etok, ep, ecnt, wdb, out);
  gather_kernel<<<NE * CAP / 8, 256, 0, stream>>>(x, etok, ecnt, Xe);
  gemm1_swiglu_bf<<<8 * 172, 512, 0, stream>>>(Xe, wgb, wub, ecnt, Hbuf);
  gemm2_down_bf<<<8 * 64, 512, 0, stream>>>(Hbuf, wdb, ecnt, etok, ep, out);
}